// Round 2
// baseline (196.476 us; speedup 1.0000x reference)
//
#include <hip/hip_runtime.h>
#include <hip/hip_bf16.h>

// GATv2: G=80 graphs (B*T), N=1000 nodes, F=64 in, H=1 head, C=64 out,
// E=8000 edges (+N self loops). Output [G,N,64].
// Runtime dtype detection: float inputs may be fp32 or bf16; edge_index may be
// int32 or int64 (low-word little-endian). flags in ws: [0]=x_is_fp32, [1]=ei_stride.

#define GG 80
#define NN 1000
#define EE 8000
#define NEG_SLOPE 0.2f

// ---------------- dtype detector ----------------
__global__ __launch_bounds__(256) void detect_kernel(
    const unsigned short* __restrict__ xw,
    const int* __restrict__ eiw,
    int* __restrict__ flags)
{
    __shared__ int bad;     // x-as-bf16 contains NaN/huge -> underlying fp32
    __shared__ int odd_nz;  // any odd int32 word nonzero -> int32 edge_index
    if (threadIdx.x == 0) { bad = 0; odd_nz = 0; }
    __syncthreads();
    for (int i = threadIdx.x; i < 16384; i += 256) {
        unsigned int u = ((unsigned int)xw[i]) << 16;
        float f = __uint_as_float(u);
        if (!(fabsf(f) <= 1e20f)) bad = 1;  // catches NaN and |v|>1e20 (benign race)
    }
    for (int i = threadIdx.x; i < EE; i += 256) {
        if (eiw[2 * i + 1] != 0) odd_nz = 1;
    }
    __syncthreads();
    if (threadIdx.x == 0) {
        flags[0] = bad;               // 1 => fp32 float inputs (and fp32 output)
        flags[1] = odd_nz ? 1 : 2;    // int32 stride 1 / int64 stride 2
    }
}

// ---------------- Projection: XL = x@w_l, XR = x@w_r (bf16 in ws) ----------------
__global__ __launch_bounds__(256) void proj_kernel(
    const void* __restrict__ xv,
    const void* __restrict__ wlv,
    const void* __restrict__ wrv,
    __hip_bfloat16* __restrict__ XL,
    __hip_bfloat16* __restrict__ XR,
    const int* __restrict__ flags)
{
    __shared__ float Wl[64 * 64];
    __shared__ float Wr[64 * 64];
    __shared__ float Xs[64 * 68];  // [k][r] transposed, stride 68 (16B-aligned rows)
    const int t = threadIdx.x;
    const int rb = blockIdx.x * 64;
    const bool fp32 = (flags[0] != 0);

    if (fp32) {
        const float* x  = (const float*)xv;
        const float* wl = (const float*)wlv;
        const float* wr = (const float*)wrv;
        for (int i = t; i < 4096; i += 256) { Wl[i] = wl[i]; Wr[i] = wr[i]; }
        for (int i = t; i < 4096; i += 256) {
            int r = i >> 6, k = i & 63;
            Xs[k * 68 + r] = x[(size_t)(rb + r) * 64 + k];
        }
    } else {
        const __hip_bfloat16* x  = (const __hip_bfloat16*)xv;
        const __hip_bfloat16* wl = (const __hip_bfloat16*)wlv;
        const __hip_bfloat16* wr = (const __hip_bfloat16*)wrv;
        for (int i = t; i < 4096; i += 256) {
            Wl[i] = __bfloat162float(wl[i]);
            Wr[i] = __bfloat162float(wr[i]);
        }
        for (int i = t; i < 4096; i += 256) {
            int r = i >> 6, k = i & 63;
            Xs[k * 68 + r] = __bfloat162float(x[(size_t)(rb + r) * 64 + k]);
        }
    }
    __syncthreads();

    const int c = t & 63;
    const int rg = t >> 6;
    float accl[16], accr[16];
#pragma unroll
    for (int j = 0; j < 16; j++) { accl[j] = 0.f; accr[j] = 0.f; }

    for (int k = 0; k < 64; k++) {
        float a = Wl[k * 64 + c];
        float b = Wr[k * 64 + c];
        const float4* xp = (const float4*)(&Xs[k * 68 + rg * 16]);
#pragma unroll
        for (int q = 0; q < 4; q++) {
            float4 xv4 = xp[q];
            accl[q * 4 + 0] += xv4.x * a;  accr[q * 4 + 0] += xv4.x * b;
            accl[q * 4 + 1] += xv4.y * a;  accr[q * 4 + 1] += xv4.y * b;
            accl[q * 4 + 2] += xv4.z * a;  accr[q * 4 + 2] += xv4.z * b;
            accl[q * 4 + 3] += xv4.w * a;  accr[q * 4 + 3] += xv4.w * b;
        }
    }
#pragma unroll
    for (int j = 0; j < 16; j++) {
        size_t row = (size_t)rb + rg * 16 + j;
        XL[row * 64 + c] = __float2bfloat16(accl[j]);
        XR[row * 64 + c] = __float2bfloat16(accr[j]);
    }
}

// ---------------- CSR build by dst (counting sort), single block ----------------
__global__ __launch_bounds__(1024) void csr_kernel(
    const int* __restrict__ ei, const int* __restrict__ flags,
    int* __restrict__ off, int* __restrict__ list)
{
    __shared__ int cnt[1024];
    __shared__ int scn[1024];
    __shared__ int cur[1024];
    const int t = threadIdx.x;
    const int stride = flags[1];

    cnt[t] = (t < NN) ? 1 : 0;  // self loop pre-counted
    __syncthreads();
    for (int e = t; e < EE; e += 1024) {
        int d = ei[(size_t)(EE + e) * stride];
        atomicAdd(&cnt[d], 1);
    }
    __syncthreads();
    scn[t] = cnt[t];
    __syncthreads();
    for (int ofs = 1; ofs < 1024; ofs <<= 1) {
        int add = (t >= ofs) ? scn[t - ofs] : 0;
        __syncthreads();
        scn[t] += add;
        __syncthreads();
    }
    int excl = (t == 0) ? 0 : scn[t - 1];
    if (t <= NN) off[t] = excl;
    if (t < NN) cur[t] = excl;
    __syncthreads();
    for (int e = t; e < EE; e += 1024) {
        int d = ei[(size_t)(EE + e) * stride];
        int s = ei[(size_t)e * stride];
        int p = atomicAdd(&cur[d], 1);
        list[p] = s;
    }
    for (int n = t; n < NN; n += 1024) {
        int p = atomicAdd(&cur[n], 1);
        list[p] = n;
    }
}

// ---------------- Aggregation: one wave per (dst d, graph g), lane = channel ----------------
__global__ __launch_bounds__(256) void agg_kernel(
    const __hip_bfloat16* __restrict__ XL,
    const __hip_bfloat16* __restrict__ XR,
    const int* __restrict__ off,
    const int* __restrict__ list,
    const void* __restrict__ attv,
    const void* __restrict__ biasv,
    void* __restrict__ outv,
    const int* __restrict__ flags)
{
    const int wid = (blockIdx.x << 2) + (threadIdx.x >> 6);
    const int lane = threadIdx.x & 63;
    const int d = wid / GG;
    const int g = wid - d * GG;
    const bool fp32 = (flags[0] != 0);

    float attc, biasc;
    if (fp32) {
        attc  = ((const float*)attv)[lane];
        biasc = ((const float*)biasv)[lane];
    } else {
        attc  = __bfloat162float(((const __hip_bfloat16*)attv)[lane]);
        biasc = __bfloat162float(((const __hip_bfloat16*)biasv)[lane]);
    }
    const float xrc = __bfloat162float(XR[((size_t)g * NN + d) * 64 + lane]);
    const int beg = off[d];
    const int end = off[d + 1];

    // peeled first edge (degree >= 1 guaranteed by self loop): all exp args bounded
    int s0 = list[beg];
    float xlc = __bfloat162float(XL[((size_t)g * NN + s0) * 64 + lane]);
    float v = xlc + xrc;
    v = (v > 0.f) ? v : NEG_SLOPE * v;
    float p = v * attc;
#pragma unroll
    for (int msk = 32; msk >= 1; msk >>= 1) p += __shfl_xor(p, msk, 64);
    float m = p, l = 1.f, o = xlc;

    for (int e = beg + 1; e < end; e++) {
        int s = list[e];
        xlc = __bfloat162float(XL[((size_t)g * NN + s) * 64 + lane]);
        v = xlc + xrc;
        v = (v > 0.f) ? v : NEG_SLOPE * v;
        p = v * attc;
#pragma unroll
        for (int msk = 32; msk >= 1; msk >>= 1) p += __shfl_xor(p, msk, 64);
        float nm = fmaxf(m, p);
        float sc = __expf(m - nm);
        float w  = __expf(p - nm);
        o = o * sc + w * xlc;
        l = l * sc + w;
        m = nm;
    }
    float res = o / l + biasc;
    if (fp32) ((float*)outv)[((size_t)g * NN + d) * 64 + lane] = res;
    else ((__hip_bfloat16*)outv)[((size_t)g * NN + d) * 64 + lane] = __float2bfloat16(res);
}

extern "C" void kernel_launch(void* const* d_in, const int* in_sizes, int n_in,
                              void* d_out, int out_size, void* d_ws, size_t ws_size,
                              hipStream_t stream) {
    const void* x    = d_in[0];
    const int*  ei   = (const int*)d_in[1];
    const void* wl   = d_in[2];
    const void* wr   = d_in[3];
    const void* att  = d_in[4];
    const void* bias = d_in[5];

    char* ws = (char*)d_ws;
    int* flags = (int*)ws;                       // 2 ints (padded to 64)
    int* off   = flags + 64;                     // 1001 ints (padded to 1088)
    int* list  = off + 1088;                     // 9000 ints
    __hip_bfloat16* XL = (__hip_bfloat16*)(ws + 65536);   // 5.12M bf16
    __hip_bfloat16* XR = XL + (size_t)GG * NN * 64;       // 5.12M bf16
    // total ws use: 65536 + 20,480,000 bytes

    hipLaunchKernelGGL(detect_kernel, dim3(1), dim3(256), 0, stream,
                       (const unsigned short*)x, ei, flags);
    hipLaunchKernelGGL(csr_kernel, dim3(1), dim3(1024), 0, stream, ei, flags, off, list);
    hipLaunchKernelGGL(proj_kernel, dim3((GG * NN) / 64), dim3(256), 0, stream,
                       x, wl, wr, XL, XR, flags);
    hipLaunchKernelGGL(agg_kernel, dim3((NN * GG) / 4), dim3(256), 0, stream,
                       XL, XR, off, list, att, bias, d_out, flags);
}

// Round 3
// 134.703 us; speedup vs baseline: 1.4586x; 1.4586x over previous
//
#include <hip/hip_runtime.h>
#include <hip/hip_bf16.h>

// GATv2 on MI355X. G=80 graphs, N=1000 nodes, F=C=64, H=1, E=8000 (+N self loops).
// Evidence R2: inputs fp32 (WRITE_SIZE=20MB fp32 out), edge_index width still runtime-probed.
// Plan: proj writes XLt/XRt transposed [n][g][c] bf16; agg = 1 block per dst node,
// thread (g,cg) owns 8 channels; per-edge: 1 dwordx4 load + 8 fma + 3-shfl octet reduce;
// softmax without max-subtraction (logits bounded) => plain weighted accumulation.

#define GG 80
#define NN 1000
#define EE 8000
#define NEG_SLOPE 0.2f

// ---------------- Projection: XLt/XRt[n][g][c] = (x @ w_l/w_r), bf16 ----------------
__global__ __launch_bounds__(256) void proj_kernel(
    const float* __restrict__ x,
    const float* __restrict__ wl,
    const float* __restrict__ wr,
    __hip_bfloat16* __restrict__ XLt,
    __hip_bfloat16* __restrict__ XRt)
{
    __shared__ float Wl[64 * 64];
    __shared__ float Wr[64 * 64];
    __shared__ float Xs[64 * 68];  // [k][r] transposed, stride 68 keeps float4 alignment
    const int t = threadIdx.x;
    const int rb = blockIdx.x * 64;

    for (int i = t; i < 4096; i += 256) { Wl[i] = wl[i]; Wr[i] = wr[i]; }
    for (int i = t; i < 4096; i += 256) {
        int r = i >> 6, k = i & 63;
        Xs[k * 68 + r] = x[(size_t)(rb + r) * 64 + k];
    }
    __syncthreads();

    const int c = t & 63;
    const int rg = t >> 6;           // rows rg*16 .. rg*16+15
    float accl[16], accr[16];
#pragma unroll
    for (int j = 0; j < 16; j++) { accl[j] = 0.f; accr[j] = 0.f; }

    for (int k = 0; k < 64; k++) {
        float a = Wl[k * 64 + c];
        float b = Wr[k * 64 + c];
        const float4* xp = (const float4*)(&Xs[k * 68 + rg * 16]);  // wave-uniform -> broadcast
#pragma unroll
        for (int q = 0; q < 4; q++) {
            float4 xv = xp[q];
            accl[q * 4 + 0] += xv.x * a;  accr[q * 4 + 0] += xv.x * b;
            accl[q * 4 + 1] += xv.y * a;  accr[q * 4 + 1] += xv.y * b;
            accl[q * 4 + 2] += xv.z * a;  accr[q * 4 + 2] += xv.z * b;
            accl[q * 4 + 3] += xv.w * a;  accr[q * 4 + 3] += xv.w * b;
        }
    }
#pragma unroll
    for (int j = 0; j < 16; j++) {
        int row = rb + rg * 16 + j;        // row = g*NN + n
        int g = row / NN;
        int n = row - g * NN;
        size_t o = ((size_t)n * GG + g) * 64 + c;
        XLt[o] = __float2bfloat16(accl[j]);
        XRt[o] = __float2bfloat16(accr[j]);
    }
}

// ---------------- Aggregation: one block (640 thr) per dst node d ----------------
// thread t: g = t>>3 (0..79), cg = t&7 -> channels cg*8..cg*8+7. Octet (same g) is
// 8 consecutive lanes -> 3-stage shfl_xor reduce, no LDS/sync in edge loop.
__global__ __launch_bounds__(640) void agg_kernel(
    const __hip_bfloat16* __restrict__ XLt,
    const __hip_bfloat16* __restrict__ XRt,
    const int* __restrict__ ei32,
    const float* __restrict__ att,
    const float* __restrict__ bias,
    float* __restrict__ out)
{
    __shared__ int elist[1024];
    __shared__ int s_cnt;
    __shared__ int s_odd;
    const int t = threadIdx.x;
    const int d = blockIdx.x;
    const int g = t >> 3;
    const int cg = t & 7;

    // --- edge-index width probe: int64 low-word LE (odd int32 words all 0) vs int32 ---
    if (t == 0) { s_cnt = 0; s_odd = 0; }
    __syncthreads();
    for (int e = t; e < 2048; e += 640)
        if (ei32[2 * e + 1] != 0) s_odd = 1;   // indices < 4096: safe for both widths
    __syncthreads();
    const int stride = s_odd ? 1 : 2;

    // --- gather this node's incoming edges (src ids) into LDS ---
    for (int e = t; e < EE; e += 640) {
        int de = ei32[(size_t)(EE + e) * stride];
        if (de == d) {
            int p = atomicAdd(&s_cnt, 1);
            if (p < 1023) elist[p] = ei32[(size_t)e * stride];
        }
    }
    __syncthreads();
    if (t == 0) { elist[min(s_cnt, 1023)] = d; s_cnt = min(s_cnt, 1023) + 1; }  // self loop
    __syncthreads();
    const int cnt = s_cnt;

    // --- per-thread constants ---
    float xr[8], av[8];
    {
        const uint4 u = *(const uint4*)((const unsigned short*)XRt + ((size_t)d * GG + g) * 64 + cg * 8);
        const unsigned int uw[4] = {u.x, u.y, u.z, u.w};
#pragma unroll
        for (int q = 0; q < 4; q++) {
            xr[2 * q + 0] = __uint_as_float(uw[q] << 16);
            xr[2 * q + 1] = __uint_as_float(uw[q] & 0xffff0000u);
        }
#pragma unroll
        for (int j = 0; j < 8; j++) av[j] = att[cg * 8 + j];
    }

    float acc[8];
#pragma unroll
    for (int j = 0; j < 8; j++) acc[j] = 0.f;
    float dn = 0.f;

    for (int i = 0; i < cnt; i++) {
        int s = elist[i];                      // LDS broadcast
        const uint4 u = *(const uint4*)((const unsigned short*)XLt + ((size_t)s * GG + g) * 64 + cg * 8);
        const unsigned int uw[4] = {u.x, u.y, u.z, u.w};
        float xf[8];
#pragma unroll
        for (int q = 0; q < 4; q++) {
            xf[2 * q + 0] = __uint_as_float(uw[q] << 16);
            xf[2 * q + 1] = __uint_as_float(uw[q] & 0xffff0000u);
        }
        float p = 0.f;
#pragma unroll
        for (int j = 0; j < 8; j++) {
            float v = xf[j] + xr[j];
            float lv = fmaxf(v, 0.f) + NEG_SLOPE * fminf(v, 0.f);
            p = fmaf(av[j], lv, p);
        }
        p += __shfl_xor(p, 1, 64);
        p += __shfl_xor(p, 2, 64);
        p += __shfl_xor(p, 4, 64);             // all 8 octet lanes hold the logit
        float w = __expf(p);                   // no max-shift: |logit| bounded ~10
        dn += w;
#pragma unroll
        for (int j = 0; j < 8; j++) acc[j] = fmaf(w, xf[j], acc[j]);
    }

    const float inv = 1.f / dn;
    float4 r0, r1;
    r0.x = acc[0] * inv + bias[cg * 8 + 0];
    r0.y = acc[1] * inv + bias[cg * 8 + 1];
    r0.z = acc[2] * inv + bias[cg * 8 + 2];
    r0.w = acc[3] * inv + bias[cg * 8 + 3];
    r1.x = acc[4] * inv + bias[cg * 8 + 4];
    r1.y = acc[5] * inv + bias[cg * 8 + 5];
    r1.z = acc[6] * inv + bias[cg * 8 + 6];
    r1.w = acc[7] * inv + bias[cg * 8 + 7];
    float* po = out + ((size_t)g * NN + d) * 64 + cg * 8;
    *(float4*)po = r0;
    *(float4*)(po + 4) = r1;
}

extern "C" void kernel_launch(void* const* d_in, const int* in_sizes, int n_in,
                              void* d_out, int out_size, void* d_ws, size_t ws_size,
                              hipStream_t stream) {
    const float* x    = (const float*)d_in[0];
    const int*   ei   = (const int*)d_in[1];
    const float* wl   = (const float*)d_in[2];
    const float* wr   = (const float*)d_in[3];
    const float* att  = (const float*)d_in[4];
    const float* bias = (const float*)d_in[5];
    float* out = (float*)d_out;

    char* ws = (char*)d_ws;
    __hip_bfloat16* XLt = (__hip_bfloat16*)ws;               // [N][G][64] bf16 = 10.24 MB
    __hip_bfloat16* XRt = XLt + (size_t)NN * GG * 64;        // + 10.24 MB

    hipLaunchKernelGGL(proj_kernel, dim3((GG * NN) / 64), dim3(256), 0, stream,
                       x, wl, wr, XLt, XRt);
    hipLaunchKernelGGL(agg_kernel, dim3(NN), dim3(640), 0, stream,
                       XLt, XRt, ei, att, bias, out);
}

// Round 4
// 120.966 us; speedup vs baseline: 1.6242x; 1.1136x over previous
//
#include <hip/hip_runtime.h>
#include <hip/hip_bf16.h>

// GATv2 on MI355X. G=80 graphs, N=1000 nodes, F=C=64, H=1, E=8000 (+N self loops).
// fp32 inputs/outputs (confirmed R2: WRITE_SIZE=20MB). edge_index width runtime-probed.
// R4: proj rewritten with v_mfma_f32_16x16x32_bf16 (A from global fp32->bf16 frags,
// W staged bf16 in LDS [col][k] pad-72). agg unchanged from R3 (proven).

#define GG 80
#define NN 1000
#define EE 8000
#define MM 80000           // G*N rows
#define NEG_SLOPE 0.2f

typedef __attribute__((ext_vector_type(8))) short short8;    // 8 bf16 = 4 VGPRs (guide §3)
typedef __attribute__((ext_vector_type(4))) float floatx4;   // MFMA C/D

__device__ __forceinline__ unsigned short f2b(float f) {     // fp32 -> bf16 bits, RNE
    unsigned int u = __float_as_uint(f);
    unsigned int r = u + 0x7fffu + ((u >> 16) & 1u);
    return (unsigned short)(r >> 16);
}

// ---------------- Projection via MFMA: XLt/XRt[n][g][c] bf16 ----------------
// Block 256 thr = 4 waves; wave handles 64 rows (4 m-subtiles), N=128 (wl cols 0-63, wr 64-127).
__global__ __launch_bounds__(256) void proj_kernel(
    const float* __restrict__ x,
    const float* __restrict__ wl,
    const float* __restrict__ wr,
    unsigned short* __restrict__ XLt,
    unsigned short* __restrict__ XRt)
{
    __shared__ __align__(16) unsigned short Wt[128 * 72];  // [col][k], pad 72 (144B stride)
    const int t = threadIdx.x;

    // stage W -> LDS bf16 transposed (coalesced fp32 reads)
    for (int idx = t; idx < 8192; idx += 256) {
        int half = idx >> 12;                 // 0: wl, 1: wr
        int k = (idx & 4095) >> 6;
        int c = idx & 63;
        float v = half ? wr[k * 64 + c] : wl[k * 64 + c];
        Wt[(c + half * 64) * 72 + k] = f2b(v);
    }
    __syncthreads();

    const int wave = t >> 6;
    const int lane = t & 63;
    const int quad = lane >> 4;
    const int lm   = lane & 15;
    const int Rb   = (blockIdx.x * 4 + wave) * 64;

    // B fragments: Bf[ks][sub], lane holds B[k=ks*32+quad*8+j][n=sub*16+lm]
    short8 Bf[2][8];
#pragma unroll
    for (int ks = 0; ks < 2; ks++)
#pragma unroll
        for (int sub = 0; sub < 8; sub++)
            Bf[ks][sub] = *(const short8*)(&Wt[(sub * 16 + lm) * 72 + ks * 32 + quad * 8]);

    const float4* x4 = (const float4*)x;  // row = 16 float4

#pragma unroll
    for (int sm = 0; sm < 4; sm++) {
        const int rbase = Rb + sm * 16;
        const int r  = rbase + lm;
        const int rc = (r < MM) ? r : (MM - 1);   // clamp loads; stores guarded

        // A fragments: lane holds x[r][ks*32+quad*8 .. +7]
        short8 Af[2];
#pragma unroll
        for (int ks = 0; ks < 2; ks++) {
            float4 p = x4[(size_t)rc * 16 + ks * 8 + quad * 2];
            float4 q = x4[(size_t)rc * 16 + ks * 8 + quad * 2 + 1];
            short8 a;
            a[0] = (short)f2b(p.x); a[1] = (short)f2b(p.y);
            a[2] = (short)f2b(p.z); a[3] = (short)f2b(p.w);
            a[4] = (short)f2b(q.x); a[5] = (short)f2b(q.y);
            a[6] = (short)f2b(q.z); a[7] = (short)f2b(q.w);
            Af[ks] = a;
        }

        floatx4 acc[8];
#pragma unroll
        for (int sub = 0; sub < 8; sub++) acc[sub] = (floatx4)(0.f);
#pragma unroll
        for (int ks = 0; ks < 2; ks++)
#pragma unroll
            for (int sub = 0; sub < 8; sub++)
                acc[sub] = __builtin_amdgcn_mfma_f32_16x16x32_bf16(Af[ks], Bf[ks][sub], acc[sub], 0, 0, 0);

        // D: col = lm (within subtile), row = quad*4 + reg
#pragma unroll
        for (int reg = 0; reg < 4; reg++) {
            int rr = rbase + quad * 4 + reg;
            if (rr < MM) {
                int g = rr / 1000;
                int n = rr - g * 1000;
                size_t ob = ((size_t)n * GG + g) * 64 + lm;
#pragma unroll
                for (int sub = 0; sub < 4; sub++)
                    XLt[ob + sub * 16] = f2b(acc[sub][reg]);
#pragma unroll
                for (int sub = 4; sub < 8; sub++)
                    XRt[ob + (sub - 4) * 16] = f2b(acc[sub][reg]);
            }
        }
    }
}

// ---------------- Aggregation: one block (640 thr) per dst node d ----------------
// thread t: g = t>>3 (0..79), cg = t&7 -> channels cg*8..cg*8+7. Octet = 8 consecutive
// lanes -> 3-stage shfl_xor reduce; softmax without max-shift (logits bounded).
__global__ __launch_bounds__(640) void agg_kernel(
    const unsigned short* __restrict__ XLt,
    const unsigned short* __restrict__ XRt,
    const int* __restrict__ ei32,
    const float* __restrict__ att,
    const float* __restrict__ bias,
    float* __restrict__ out)
{
    __shared__ int elist[1024];
    __shared__ int s_cnt;
    __shared__ int s_odd;
    const int t = threadIdx.x;
    const int d = blockIdx.x;
    const int g = t >> 3;
    const int cg = t & 7;

    if (t == 0) { s_cnt = 0; s_odd = 0; }
    __syncthreads();
    for (int e = t; e < 2048; e += 640)
        if (ei32[2 * e + 1] != 0) s_odd = 1;   // int32 vs int64(LE) probe
    __syncthreads();
    const int stride = s_odd ? 1 : 2;

    for (int e = t; e < EE; e += 640) {
        int de = ei32[(size_t)(EE + e) * stride];
        if (de == d) {
            int p = atomicAdd(&s_cnt, 1);
            if (p < 1023) elist[p] = ei32[(size_t)e * stride];
        }
    }
    __syncthreads();
    if (t == 0) { elist[min(s_cnt, 1023)] = d; s_cnt = min(s_cnt, 1023) + 1; }  // self loop
    __syncthreads();
    const int cnt = s_cnt;

    float xr[8], av[8];
    {
        const uint4 u = *(const uint4*)(XRt + ((size_t)d * GG + g) * 64 + cg * 8);
        const unsigned int uw[4] = {u.x, u.y, u.z, u.w};
#pragma unroll
        for (int q = 0; q < 4; q++) {
            xr[2 * q + 0] = __uint_as_float(uw[q] << 16);
            xr[2 * q + 1] = __uint_as_float(uw[q] & 0xffff0000u);
        }
#pragma unroll
        for (int j = 0; j < 8; j++) av[j] = att[cg * 8 + j];
    }

    float acc[8];
#pragma unroll
    for (int j = 0; j < 8; j++) acc[j] = 0.f;
    float dn = 0.f;

    for (int i = 0; i < cnt; i++) {
        int s = elist[i];
        const uint4 u = *(const uint4*)(XLt + ((size_t)s * GG + g) * 64 + cg * 8);
        const unsigned int uw[4] = {u.x, u.y, u.z, u.w};
        float xf[8];
#pragma unroll
        for (int q = 0; q < 4; q++) {
            xf[2 * q + 0] = __uint_as_float(uw[q] << 16);
            xf[2 * q + 1] = __uint_as_float(uw[q] & 0xffff0000u);
        }
        float p = 0.f;
#pragma unroll
        for (int j = 0; j < 8; j++) {
            float v = xf[j] + xr[j];
            float lv = fmaxf(v, 0.f) + NEG_SLOPE * fminf(v, 0.f);
            p = fmaf(av[j], lv, p);
        }
        p += __shfl_xor(p, 1, 64);
        p += __shfl_xor(p, 2, 64);
        p += __shfl_xor(p, 4, 64);
        float w = __expf(p);
        dn += w;
#pragma unroll
        for (int j = 0; j < 8; j++) acc[j] = fmaf(w, xf[j], acc[j]);
    }

    const float inv = 1.f / dn;
    float4 r0, r1;
    r0.x = acc[0] * inv + bias[cg * 8 + 0];
    r0.y = acc[1] * inv + bias[cg * 8 + 1];
    r0.z = acc[2] * inv + bias[cg * 8 + 2];
    r0.w = acc[3] * inv + bias[cg * 8 + 3];
    r1.x = acc[4] * inv + bias[cg * 8 + 4];
    r1.y = acc[5] * inv + bias[cg * 8 + 5];
    r1.z = acc[6] * inv + bias[cg * 8 + 6];
    r1.w = acc[7] * inv + bias[cg * 8 + 7];
    float* po = out + ((size_t)g * NN + d) * 64 + cg * 8;
    *(float4*)po = r0;
    *(float4*)(po + 4) = r1;
}

extern "C" void kernel_launch(void* const* d_in, const int* in_sizes, int n_in,
                              void* d_out, int out_size, void* d_ws, size_t ws_size,
                              hipStream_t stream) {
    const float* x    = (const float*)d_in[0];
    const int*   ei   = (const int*)d_in[1];
    const float* wl   = (const float*)d_in[2];
    const float* wr   = (const float*)d_in[3];
    const float* att  = (const float*)d_in[4];
    const float* bias = (const float*)d_in[5];
    float* out = (float*)d_out;

    char* ws = (char*)d_ws;
    unsigned short* XLt = (unsigned short*)ws;               // [N][G][64] bf16 = 10.24 MB
    unsigned short* XRt = XLt + (size_t)NN * GG * 64;        // + 10.24 MB

    hipLaunchKernelGGL(proj_kernel, dim3((MM + 255) / 256), dim3(256), 0, stream,
                       x, wl, wr, XLt, XRt);
    hipLaunchKernelGGL(agg_kernel, dim3(NN), dim3(640), 0, stream,
                       XLt, XRt, ei, att, bias, out);
}